// Round 1
// baseline (397.698 us; speedup 1.0000x reference)
//
#include <hip/hip_runtime.h>

#define S_ATOMS 28
#define FEA 2048
#define HID 1024
#define JK 84            // NAT*3
#define HB_PER_S 64      // h-blocks per species in k1 (16 rows each)
#define ENE_SLOTS 256
#define NBLK2 (S_ATOMS * JK / 4)   // 588 dot blocks; block NBLK2 finalizes energy

// ---------------- Kernel 1: fused forward matvec + ReLU + backward g ----------------
// grid = S_ATOMS * HB_PER_S = 1792 blocks, 256 threads (4 waves), wave handles 4 rows.
__global__ __launch_bounds__(256) void bpnn_k1(
    const float* __restrict__ des, const float* __restrict__ W1,
    const float* __restrict__ b1,  const float* __restrict__ W2,
    float* __restrict__ g, float* __restrict__ ene_slots)
{
    const int s    = blockIdx.x / HB_PER_S;
    const int hb   = blockIdx.x % HB_PER_S;
    const int wave = threadIdx.x >> 6;
    const int lane = threadIdx.x & 63;

    // des slice: lane owns f = c*256 + lane*4 .. +3, c = 0..7  (32 floats)
    const float* desS = des + (size_t)s * FEA;
    float4 d[8];
#pragma unroll
    for (int c = 0; c < 8; ++c)
        d[c] = *reinterpret_cast<const float4*>(desS + c * 256 + lane * 4);

    float4 gacc[8];
#pragma unroll
    for (int c = 0; c < 8; ++c) gacc[c] = make_float4(0.f, 0.f, 0.f, 0.f);
    float eacc = 0.f;

    const int h0 = hb * 16 + wave * 4;
#pragma unroll
    for (int r = 0; r < 4; ++r) {
        const int h = h0 + r;
        const float* w = W1 + ((size_t)s * HID + h) * FEA;
        float4 wv[8];
#pragma unroll
        for (int c = 0; c < 8; ++c)
            wv[c] = *reinterpret_cast<const float4*>(w + c * 256 + lane * 4);
        float dot = 0.f;
#pragma unroll
        for (int c = 0; c < 8; ++c) {
            dot = fmaf(wv[c].x, d[c].x, dot);
            dot = fmaf(wv[c].y, d[c].y, dot);
            dot = fmaf(wv[c].z, d[c].z, dot);
            dot = fmaf(wv[c].w, d[c].w, dot);
        }
#pragma unroll
        for (int m = 1; m < 64; m <<= 1)
            dot += __shfl_xor(dot, m, 64);
        const float hpre = dot + b1[s * HID + h];   // uniform across wave
        if (hpre > 0.f) {                            // wave-uniform branch
            const float c2 = W2[s * HID + h];
            eacc = fmaf(hpre, c2, eacc);
#pragma unroll
            for (int c = 0; c < 8; ++c) {
                gacc[c].x = fmaf(c2, wv[c].x, gacc[c].x);
                gacc[c].y = fmaf(c2, wv[c].y, gacc[c].y);
                gacc[c].z = fmaf(c2, wv[c].z, gacc[c].z);
                gacc[c].w = fmaf(c2, wv[c].w, gacc[c].w);
            }
        }
    }

    // ---- combine the 4 waves' g in LDS (permuted layout: lane-stride-1, no bank conflicts) ----
    __shared__ float gs[FEA];
    __shared__ float es[4];
    for (int i = threadIdx.x; i < FEA; i += 256) gs[i] = 0.f;
    if (lane == 0) es[wave] = eacc;   // eacc identical across lanes
    __syncthreads();
#pragma unroll
    for (int c = 0; c < 8; ++c) {
        atomicAdd(&gs[c * 256 +   0 + lane], gacc[c].x);
        atomicAdd(&gs[c * 256 +  64 + lane], gacc[c].y);
        atomicAdd(&gs[c * 256 + 128 + lane], gacc[c].z);
        atomicAdd(&gs[c * 256 + 192 + lane], gacc[c].w);
    }
    __syncthreads();
    // one global atomic per f per block; invert permutation p=(c,i,l) -> f=c*256+l*4+i
    for (int p = threadIdx.x; p < FEA; p += 256) {
        const int c = p >> 8;
        const int i = (p & 255) >> 6;
        const int l = p & 63;
        atomicAdd(&g[(size_t)s * FEA + c * 256 + l * 4 + i], gs[p]);
    }
    if (threadIdx.x == 0)
        atomicAdd(&ene_slots[blockIdx.x & (ENE_SLOTS - 1)], es[0] + es[1] + es[2] + es[3]);
}

// ---------------- Kernel 2: force contraction + energy finalize ----------------
// blocks 0..NBLK2-1: 4 waves, each wave does one (s,jk) dot of length 2048.
// block NBLK2: reduce energy slots + sum(b2) -> out[0].
__global__ __launch_bounds__(256) void bpnn_k2(
    const float* __restrict__ der, const float* __restrict__ g,
    const float* __restrict__ b2,  const float* __restrict__ ene_slots,
    float* __restrict__ out)
{
    if (blockIdx.x == NBLK2) {
        const int tid = threadIdx.x;
        if (tid < 64) {
            float e = ene_slots[tid] + ene_slots[tid + 64] +
                      ene_slots[tid + 128] + ene_slots[tid + 192];
#pragma unroll
            for (int m = 1; m < 64; m <<= 1)
                e += __shfl_xor(e, m, 64);
            if (tid == 0) {
                float bs = 0.f;
                for (int s = 0; s < S_ATOMS; ++s) bs += b2[s];
                out[0] = e + bs;
            }
        }
        return;
    }
    const int wave = threadIdx.x >> 6;
    const int lane = threadIdx.x & 63;
    const int id = blockIdx.x * 4 + wave;        // 0..2351
    const int s  = id / JK;
    const int jk = id % JK;
    const float* dr = der + ((size_t)s * JK + jk) * FEA;
    const float* gr = g + (size_t)s * FEA;
    float acc = 0.f;
#pragma unroll
    for (int c = 0; c < 8; ++c) {
        const float4 a = *reinterpret_cast<const float4*>(dr + c * 256 + lane * 4);
        const float4 b = *reinterpret_cast<const float4*>(gr + c * 256 + lane * 4);
        acc = fmaf(a.x, b.x, acc);
        acc = fmaf(a.y, b.y, acc);
        acc = fmaf(a.z, b.z, acc);
        acc = fmaf(a.w, b.w, acc);
    }
#pragma unroll
    for (int m = 1; m < 64; m <<= 1)
        acc += __shfl_xor(acc, m, 64);
    if (lane == 0)
        atomicAdd(&out[1 + jk], -acc);           // force = -der . g  (28 adds/address)
}

extern "C" void kernel_launch(void* const* d_in, const int* in_sizes, int n_in,
                              void* d_out, int out_size, void* d_ws, size_t ws_size,
                              hipStream_t stream) {
    const float* des = (const float*)d_in[0];
    const float* der = (const float*)d_in[1];
    const float* W1  = (const float*)d_in[2];
    const float* b1  = (const float*)d_in[3];
    const float* W2  = (const float*)d_in[4];
    const float* b2  = (const float*)d_in[5];
    float* out = (float*)d_out;

    float* g         = (float*)d_ws;                 // [28, 2048]
    float* ene_slots = g + S_ATOMS * FEA;            // [256]

    hipMemsetAsync(d_ws, 0, (size_t)(S_ATOMS * FEA + ENE_SLOTS) * sizeof(float), stream);
    hipMemsetAsync(d_out, 0, (size_t)out_size * sizeof(float), stream);

    bpnn_k1<<<S_ATOMS * HB_PER_S, 256, 0, stream>>>(des, W1, b1, W2, g, ene_slots);
    bpnn_k2<<<NBLK2 + 1, 256, 0, stream>>>(der, g, b2, ene_slots, out);
}

// Round 2
// 364.492 us; speedup vs baseline: 1.0911x; 1.0911x over previous
//
#include <hip/hip_runtime.h>

#define S_ATOMS 28
#define FEA 2048
#define HID 1024
#define JK 84            // NAT*3
#define HB_PER_S 64      // h-blocks per species in k1 (16 rows each)
#define ENE_SLOTS 256
#define NBLK2 (S_ATOMS * JK / 4)   // 588 dot blocks; block NBLK2 finalizes energy

typedef float floatx4 __attribute__((ext_vector_type(4)));

// ---------------- Kernel 1: fused forward matvec + ReLU + backward g ----------------
// grid = S_ATOMS * HB_PER_S = 1792 blocks, 256 threads (4 waves), wave handles 4 rows.
__global__ __launch_bounds__(256) void bpnn_k1(
    const float* __restrict__ des, const float* __restrict__ W1,
    const float* __restrict__ b1,  const float* __restrict__ W2,
    float* __restrict__ g, float* __restrict__ ene_slots)
{
    const int s    = blockIdx.x / HB_PER_S;
    const int hb   = blockIdx.x % HB_PER_S;
    const int wave = threadIdx.x >> 6;
    const int lane = threadIdx.x & 63;

    // des slice: lane owns f = c*256 + lane*4 .. +3, c = 0..7  (32 floats). Reused -> cached loads.
    const float* desS = des + (size_t)s * FEA;
    floatx4 d[8];
#pragma unroll
    for (int c = 0; c < 8; ++c)
        d[c] = *reinterpret_cast<const floatx4*>(desS + c * 256 + lane * 4);

    floatx4 gacc[8];
#pragma unroll
    for (int c = 0; c < 8; ++c) gacc[c] = (floatx4){0.f, 0.f, 0.f, 0.f};
    float eacc = 0.f;

    const int h0 = hb * 16 + wave * 4;
#pragma unroll
    for (int r = 0; r < 4; ++r) {
        const int h = h0 + r;
        const float* w = W1 + ((size_t)s * HID + h) * FEA;
        floatx4 wv[8];
#pragma unroll
        for (int c = 0; c < 8; ++c)
            wv[c] = __builtin_nontemporal_load(
                reinterpret_cast<const floatx4*>(w + c * 256 + lane * 4));
        // 4 independent accumulator chains: 8-deep each instead of one 32-deep chain
        float a0 = 0.f, a1 = 0.f, a2 = 0.f, a3 = 0.f;
#pragma unroll
        for (int c = 0; c < 8; ++c) {
            a0 = fmaf(wv[c].x, d[c].x, a0);
            a1 = fmaf(wv[c].y, d[c].y, a1);
            a2 = fmaf(wv[c].z, d[c].z, a2);
            a3 = fmaf(wv[c].w, d[c].w, a3);
        }
        float dot = (a0 + a1) + (a2 + a3);
#pragma unroll
        for (int m = 1; m < 64; m <<= 1)
            dot += __shfl_xor(dot, m, 64);
        const float hpre = dot + b1[s * HID + h];   // uniform across wave
        if (hpre > 0.f) {                            // wave-uniform branch
            const float c2 = W2[s * HID + h];
            eacc = fmaf(hpre, c2, eacc);
#pragma unroll
            for (int c = 0; c < 8; ++c) {
                gacc[c].x = fmaf(c2, wv[c].x, gacc[c].x);
                gacc[c].y = fmaf(c2, wv[c].y, gacc[c].y);
                gacc[c].z = fmaf(c2, wv[c].z, gacc[c].z);
                gacc[c].w = fmaf(c2, wv[c].w, gacc[c].w);
            }
        }
    }

    // ---- combine: per-wave private LDS slices (plain writes, no LDS atomics) ----
    __shared__ float gs[4][FEA];
    __shared__ float es[4];
    if (lane == 0) es[wave] = eacc;   // eacc identical across lanes
#pragma unroll
    for (int c = 0; c < 8; ++c) {
        gs[wave][c * 256 +   0 + lane] = gacc[c].x;
        gs[wave][c * 256 +  64 + lane] = gacc[c].y;
        gs[wave][c * 256 + 128 + lane] = gacc[c].z;
        gs[wave][c * 256 + 192 + lane] = gacc[c].w;
    }
    __syncthreads();
    // one global atomic per f per block; invert permutation p=(c,i,l) -> f=c*256+l*4+i
    for (int p = threadIdx.x; p < FEA; p += 256) {
        const float v = (gs[0][p] + gs[1][p]) + (gs[2][p] + gs[3][p]);
        const int c = p >> 8;
        const int i = (p & 255) >> 6;
        const int l = p & 63;
        atomicAdd(&g[(size_t)s * FEA + c * 256 + l * 4 + i], v);
    }
    if (threadIdx.x == 0)
        atomicAdd(&ene_slots[blockIdx.x & (ENE_SLOTS - 1)], es[0] + es[1] + es[2] + es[3]);
}

// ---------------- Kernel 2: force contraction + energy finalize ----------------
// blocks 0..NBLK2-1: 4 waves, each wave does one (s,jk) dot of length 2048.
// block NBLK2: reduce energy slots + sum(b2) -> out[0].
__global__ __launch_bounds__(256) void bpnn_k2(
    const float* __restrict__ der, const float* __restrict__ g,
    const float* __restrict__ b2,  const float* __restrict__ ene_slots,
    float* __restrict__ out)
{
    if (blockIdx.x == NBLK2) {
        const int tid = threadIdx.x;
        if (tid < 64) {
            float e = ene_slots[tid] + ene_slots[tid + 64] +
                      ene_slots[tid + 128] + ene_slots[tid + 192];
#pragma unroll
            for (int m = 1; m < 64; m <<= 1)
                e += __shfl_xor(e, m, 64);
            if (tid == 0) {
                float bs = 0.f;
                for (int s = 0; s < S_ATOMS; ++s) bs += b2[s];
                out[0] = e + bs;
            }
        }
        return;
    }
    const int wave = threadIdx.x >> 6;
    const int lane = threadIdx.x & 63;
    const int id = blockIdx.x * 4 + wave;        // 0..2351
    const int s  = id / JK;
    const int jk = id % JK;
    const float* dr = der + ((size_t)s * JK + jk) * FEA;
    const float* gr = g + (size_t)s * FEA;
    float a0 = 0.f, a1 = 0.f, a2 = 0.f, a3 = 0.f;
#pragma unroll
    for (int c = 0; c < 8; ++c) {
        const floatx4 a = __builtin_nontemporal_load(
            reinterpret_cast<const floatx4*>(dr + c * 256 + lane * 4));
        const floatx4 b = *reinterpret_cast<const floatx4*>(gr + c * 256 + lane * 4);
        a0 = fmaf(a.x, b.x, a0);
        a1 = fmaf(a.y, b.y, a1);
        a2 = fmaf(a.z, b.z, a2);
        a3 = fmaf(a.w, b.w, a3);
    }
    float acc = (a0 + a1) + (a2 + a3);
#pragma unroll
    for (int m = 1; m < 64; m <<= 1)
        acc += __shfl_xor(acc, m, 64);
    if (lane == 0)
        atomicAdd(&out[1 + jk], -acc);           // force = -der . g  (28 adds/address)
}

extern "C" void kernel_launch(void* const* d_in, const int* in_sizes, int n_in,
                              void* d_out, int out_size, void* d_ws, size_t ws_size,
                              hipStream_t stream) {
    const float* des = (const float*)d_in[0];
    const float* der = (const float*)d_in[1];
    const float* W1  = (const float*)d_in[2];
    const float* b1  = (const float*)d_in[3];
    const float* W2  = (const float*)d_in[4];
    const float* b2  = (const float*)d_in[5];
    float* out = (float*)d_out;

    float* g         = (float*)d_ws;                 // [28, 2048]
    float* ene_slots = g + S_ATOMS * FEA;            // [256]

    hipMemsetAsync(d_ws, 0, (size_t)(S_ATOMS * FEA + ENE_SLOTS) * sizeof(float), stream);
    hipMemsetAsync(d_out, 0, (size_t)out_size * sizeof(float), stream);

    bpnn_k1<<<S_ATOMS * HB_PER_S, 256, 0, stream>>>(des, W1, b1, W2, g, ene_slots);
    bpnn_k2<<<NBLK2 + 1, 256, 0, stream>>>(der, g, b2, ene_slots, out);
}

// Round 3
// 337.778 us; speedup vs baseline: 1.1774x; 1.0791x over previous
//
#include <hip/hip_runtime.h>

#define S_ATOMS 28
#define FEA 2048
#define HID 1024
#define JK 84            // NAT*3
#define HB_PER_S 64      // h-blocks per species in k1 (16 rows each)
#define NBLK1 (S_ATOMS * HB_PER_S)   // 1792
#define NBLK2 (S_ATOMS * JK / 4)     // 588 dot blocks; block NBLK2 finalizes energy

typedef float floatx4 __attribute__((ext_vector_type(4)));

// ws layout: g_p[28*2048] (permuted) | g_part[1792*2048] (permuted) | ene_part[1792]
// permuted p-space: p = c*256 + i*64 + l  <->  f = c*256 + l*4 + i   (c=f>>8, l lane, i 0..3)

// ---------------- Kernel 1: fused forward matvec + ReLU + backward g partials ----------------
// grid = 1792 blocks, 256 threads (4 waves), wave handles 4 rows. No atomics.
__global__ __launch_bounds__(256) void bpnn_k1(
    const float* __restrict__ des, const float* __restrict__ W1,
    const float* __restrict__ b1,  const float* __restrict__ W2,
    float* __restrict__ g_part, float* __restrict__ ene_part)
{
    const int s    = blockIdx.x / HB_PER_S;
    const int hb   = blockIdx.x % HB_PER_S;
    const int wave = threadIdx.x >> 6;
    const int lane = threadIdx.x & 63;

    // des slice: lane owns f = c*256 + lane*4 .. +3, c = 0..7  (32 floats). Reused -> cached loads.
    const float* desS = des + (size_t)s * FEA;
    floatx4 d[8];
#pragma unroll
    for (int c = 0; c < 8; ++c)
        d[c] = *reinterpret_cast<const floatx4*>(desS + c * 256 + lane * 4);

    floatx4 gacc[8];
#pragma unroll
    for (int c = 0; c < 8; ++c) gacc[c] = (floatx4){0.f, 0.f, 0.f, 0.f};
    float eacc = 0.f;

    const int h0 = hb * 16 + wave * 4;
#pragma unroll
    for (int r = 0; r < 4; ++r) {
        const int h = h0 + r;
        const float* w = W1 + ((size_t)s * HID + h) * FEA;
        floatx4 wv[8];
#pragma unroll
        for (int c = 0; c < 8; ++c)
            wv[c] = __builtin_nontemporal_load(
                reinterpret_cast<const floatx4*>(w + c * 256 + lane * 4));
        // 4 independent accumulator chains instead of one 32-deep chain
        float a0 = 0.f, a1 = 0.f, a2 = 0.f, a3 = 0.f;
#pragma unroll
        for (int c = 0; c < 8; ++c) {
            a0 = fmaf(wv[c].x, d[c].x, a0);
            a1 = fmaf(wv[c].y, d[c].y, a1);
            a2 = fmaf(wv[c].z, d[c].z, a2);
            a3 = fmaf(wv[c].w, d[c].w, a3);
        }
        float dot = (a0 + a1) + (a2 + a3);
#pragma unroll
        for (int m = 1; m < 64; m <<= 1)
            dot += __shfl_xor(dot, m, 64);
        const float hpre = dot + b1[s * HID + h];   // uniform across wave
        if (hpre > 0.f) {                            // wave-uniform branch
            const float c2 = W2[s * HID + h];
            eacc = fmaf(hpre, c2, eacc);
#pragma unroll
            for (int c = 0; c < 8; ++c) {
                gacc[c].x = fmaf(c2, wv[c].x, gacc[c].x);
                gacc[c].y = fmaf(c2, wv[c].y, gacc[c].y);
                gacc[c].z = fmaf(c2, wv[c].z, gacc[c].z);
                gacc[c].w = fmaf(c2, wv[c].w, gacc[c].w);
            }
        }
    }

    // ---- combine 4 waves in LDS (p-layout: lane-stride-1, conflict-free), plain stores out ----
    __shared__ float gs[4][FEA];
    __shared__ float es[4];
    if (lane == 0) es[wave] = eacc;   // eacc identical across lanes
#pragma unroll
    for (int c = 0; c < 8; ++c) {
        gs[wave][c * 256 +   0 + lane] = gacc[c].x;
        gs[wave][c * 256 +  64 + lane] = gacc[c].y;
        gs[wave][c * 256 + 128 + lane] = gacc[c].z;
        gs[wave][c * 256 + 192 + lane] = gacc[c].w;
    }
    __syncthreads();
    float* part = g_part + (size_t)blockIdx.x * FEA;   // stays in p-layout
#pragma unroll
    for (int q = 0; q < 8; ++q) {
        const int p = q * 256 + threadIdx.x;
        const float v = (gs[0][p] + gs[1][p]) + (gs[2][p] + gs[3][p]);
        __builtin_nontemporal_store(v, &part[p]);
    }
    if (threadIdx.x == 0)
        ene_part[blockIdx.x] = (es[0] + es[1]) + (es[2] + es[3]);
}

// ---------------- Kernel 1r: reduce 64 partials per species -> g_p (p-layout) ----------------
// grid = 28 * 8 = 224 blocks, 256 threads; fully coalesced both directions.
__global__ __launch_bounds__(256) void bpnn_k1r(
    const float* __restrict__ g_part, float* __restrict__ g_p)
{
    const int s     = blockIdx.x >> 3;
    const int chunk = blockIdx.x & 7;
    const int p     = chunk * 256 + threadIdx.x;
    const float* base = g_part + (size_t)s * HB_PER_S * FEA + p;
    float a0 = 0.f, a1 = 0.f, a2 = 0.f, a3 = 0.f;
#pragma unroll
    for (int hb = 0; hb < HB_PER_S; hb += 4) {
        a0 += __builtin_nontemporal_load(&base[(size_t)(hb    ) * FEA]);
        a1 += __builtin_nontemporal_load(&base[(size_t)(hb + 1) * FEA]);
        a2 += __builtin_nontemporal_load(&base[(size_t)(hb + 2) * FEA]);
        a3 += __builtin_nontemporal_load(&base[(size_t)(hb + 3) * FEA]);
    }
    g_p[s * FEA + p] = (a0 + a1) + (a2 + a3);
}

// ---------------- Kernel 2: force contraction + energy finalize ----------------
// blocks 0..NBLK2-1: 4 waves, each wave one (s,jk) dot of length 2048 (g in p-layout).
// block NBLK2: reduce ene_part + sum(b2) -> out[0].
__global__ __launch_bounds__(256) void bpnn_k2(
    const float* __restrict__ der, const float* __restrict__ g_p,
    const float* __restrict__ b2,  const float* __restrict__ ene_part,
    float* __restrict__ out)
{
    if (blockIdx.x == NBLK2) {
        const int tid = threadIdx.x;
        float e = 0.f;
        for (int i = tid; i < NBLK1; i += 256) e += ene_part[i];
        __shared__ float red[256];
        red[tid] = e;
        __syncthreads();
        if (tid < 64) {
            e = (red[tid] + red[tid + 64]) + (red[tid + 128] + red[tid + 192]);
#pragma unroll
            for (int m = 1; m < 64; m <<= 1)
                e += __shfl_xor(e, m, 64);
            if (tid == 0) {
                float bs = 0.f;
                for (int s = 0; s < S_ATOMS; ++s) bs += b2[s];
                out[0] = e + bs;
            }
        }
        return;
    }
    const int wave = threadIdx.x >> 6;
    const int lane = threadIdx.x & 63;
    const int id = blockIdx.x * 4 + wave;        // 0..2351
    const int s  = id / JK;
    const int jk = id % JK;
    const float* dr = der + ((size_t)s * JK + jk) * FEA;
    const float* gp = g_p + (size_t)s * FEA;     // 8 KB/species, reused by 21 blocks -> L2
    float a0 = 0.f, a1 = 0.f, a2 = 0.f, a3 = 0.f;
#pragma unroll
    for (int c = 0; c < 8; ++c) {
        const floatx4 a = __builtin_nontemporal_load(
            reinterpret_cast<const floatx4*>(dr + c * 256 + lane * 4));
        // g in p-layout: f=c*256+lane*4+i lives at p=c*256+i*64+lane (4 coalesced dword loads)
        const float bx = gp[c * 256 +       lane];
        const float by = gp[c * 256 +  64 + lane];
        const float bz = gp[c * 256 + 128 + lane];
        const float bw = gp[c * 256 + 192 + lane];
        a0 = fmaf(a.x, bx, a0);
        a1 = fmaf(a.y, by, a1);
        a2 = fmaf(a.z, bz, a2);
        a3 = fmaf(a.w, bw, a3);
    }
    float acc = (a0 + a1) + (a2 + a3);
#pragma unroll
    for (int m = 1; m < 64; m <<= 1)
        acc += __shfl_xor(acc, m, 64);
    if (lane == 0)
        atomicAdd(&out[1 + jk], -acc);           // 28 adds/address — negligible
}

extern "C" void kernel_launch(void* const* d_in, const int* in_sizes, int n_in,
                              void* d_out, int out_size, void* d_ws, size_t ws_size,
                              hipStream_t stream) {
    const float* des = (const float*)d_in[0];
    const float* der = (const float*)d_in[1];
    const float* W1  = (const float*)d_in[2];
    const float* b1  = (const float*)d_in[3];
    const float* W2  = (const float*)d_in[4];
    const float* b2  = (const float*)d_in[5];
    float* out = (float*)d_out;

    float* g_p      = (float*)d_ws;                        // [28*2048]
    float* g_part   = g_p + S_ATOMS * FEA;                 // [1792*2048]
    float* ene_part = g_part + (size_t)NBLK1 * FEA;        // [1792]

    // only d_out needs zeroing (force atomics); all ws buffers are fully overwritten
    hipMemsetAsync(d_out, 0, (size_t)out_size * sizeof(float), stream);

    bpnn_k1 <<<NBLK1,      256, 0, stream>>>(des, W1, b1, W2, g_part, ene_part);
    bpnn_k1r<<<S_ATOMS * 8, 256, 0, stream>>>(g_part, g_p);
    bpnn_k2 <<<NBLK2 + 1,  256, 0, stream>>>(der, g_p, b2, ene_part, out);
}